// Round 17
// baseline (84.693 us; speedup 1.0000x reference)
//
#include <hip/hip_runtime.h>
#include <hip/hip_bf16.h>

#define IN_SIZE 65536
#define HIDDEN 128
#define D_STEPS 64
#define N_ACT 512

typedef _Float16 half2_ __attribute__((ext_vector_type(2)));
typedef _Float16 half8_ __attribute__((ext_vector_type(8)));
typedef float f32x4 __attribute__((ext_vector_type(4)));

__device__ __forceinline__ float rcp_(float x) {
#if __has_builtin(__builtin_amdgcn_rcpf)
    return __builtin_amdgcn_rcpf(x);
#else
    return 1.f / x;
#endif
}
__device__ __forceinline__ float exp2_(float x) {
#if __has_builtin(__builtin_amdgcn_exp2f)
    return __builtin_amdgcn_exp2f(x);
#else
    return __exp2f(x);
#endif
}
#define L2E 1.44269504088896340736f

// ---------------- Kernel A: ihx partials (UNCHANGED from R9) ----------------
__global__ __launch_bounds__(256) void k_ihx(const float* __restrict__ w_ih,
                                             const float* __restrict__ x,
                                             float* __restrict__ partials) {
    int bid = blockIdx.x;
    int rp = bid >> 3;       // row pair 0..255
    int ck = bid & 7;        // chunk 0..7 (8192 cols each)
    int t = threadIdx.x;
    int r0 = 2 * rp, r1 = 2 * rp + 1;
    const float4* xp = (const float4*)(x + ck * 8192);
    const float4* w0 = (const float4*)(w_ih + (size_t)r0 * IN_SIZE + ck * 8192);
    const float4* w1 = (const float4*)(w_ih + (size_t)r1 * IN_SIZE + ck * 8192);

    float4 xv[8];
#pragma unroll
    for (int i = 0; i < 8; ++i) xv[i] = xp[t + i * 256];

    float a0 = 0.f, a1 = 0.f;
#pragma unroll
    for (int i = 0; i < 8; ++i) {
        float4 w4 = w0[t + i * 256];
        a0 += w4.x * xv[i].x + w4.y * xv[i].y + w4.z * xv[i].z + w4.w * xv[i].w;
    }
#pragma unroll
    for (int i = 0; i < 8; ++i) {
        float4 w4 = w1[t + i * 256];
        a1 += w4.x * xv[i].x + w4.y * xv[i].y + w4.z * xv[i].z + w4.w * xv[i].w;
    }
#pragma unroll
    for (int off = 32; off; off >>= 1) {
        a0 += __shfl_down(a0, off, 64);
        a1 += __shfl_down(a1, off, 64);
    }
    __shared__ float s[8];
    if ((t & 63) == 0) { s[t >> 6] = a0; s[4 + (t >> 6)] = a1; }
    __syncthreads();
    if (t == 0) {
        partials[r0 * 8 + ck] = s[0] + s[1] + s[2] + s[3];
        partials[r1 * 8 + ck] = s[4] + s[5] + s[6] + s[7];
    }
}

// ---------- Kernel B: 4-wave MFMA recurrence + logits (64 blocks) ----------
// R16 diagnosis: 8-wave barrier-lockstep serialized every pipe 2x per step
// (LDS 32 b128-reads, matrix pipe 2 waves/SIMD, TRANS 2x) -> ~1875 cyc/step.
// Now: wave w owns cells 32w..32w+31 for ALL 4 gates (8 row-tiles x 4 kt =
// 32 MFMA/wave), 1 wave/SIMD -> no pipe sharing; LDS reads/step halved;
// activation issues once per SIMD with col-split (lane col n<8 handles one
// cell via 28-cndmask select). afrag 32xhalf8 = 128 VGPR + ihxv 32, fits
// 1-wave/EU budget (waves_per_eu(1,1); LDS 134 KB -> 1 block/CU anyway).
__global__ __attribute__((amdgpu_flat_work_group_size(256, 256)))
__attribute__((amdgpu_waves_per_eu(1, 1)))
void k_rec_logits(
    const float* __restrict__ w_hh,
    const float* __restrict__ b_ih,
    const float* __restrict__ b_hh,
    const float* __restrict__ w_lin,
    const float* __restrict__ b_lin,
    const float* __restrict__ partials,
    float* __restrict__ out) {
    int t = threadIdx.x;     // 0..255
    int b = blockIdx.x;      // 0..63: which step this block's logits cover
    int w = t >> 6;          // wave 0..3
    int l = t & 63;
    int lg = l >> 4;         // lane group 0..3
    int n  = l & 15;         // col within tile

    __shared__ _Float16 whh_s[4 * HIDDEN * HIDDEN];  // 128 KB, f16 w_hh
    __shared__ half8_ h_v[2][16];                    // h, double-buffered
    __shared__ float h_keep[HIDDEN];
    __shared__ float ihx_s[4 * HIDDEN];              // 2 KB

    // ---- stage w_hh -> LDS as f16 (256 thr, 128 iters, unroll 8) ----
    {
        const float2* src = (const float2*)w_hh;     // 32768 float2
        half2_* dst = (half2_*)whh_s;
#pragma unroll 8
        for (int i = 0; i < 128; ++i) {
            float2 v = src[i * 256 + t];
            half2_ p = {(_Float16)v.x, (_Float16)v.y};
            dst[i * 256 + t] = p;
        }
    }
    // ---- ihx -> LDS (rows t, t+256) ----
#pragma unroll
    for (int rr = 0; rr < 2; ++rr) {
        int row = t + rr * 256;
        const float4* pp = (const float4*)(partials + row * 8);
        float4 p0 = pp[0], p1 = pp[1];
        ihx_s[row] = p0.x + p0.y + p0.z + p0.w + p1.x + p1.y + p1.z + p1.w +
                     b_ih[row] + b_hh[row];
    }
    if (t < 16) {
        half8_ z = {(_Float16)0.f, (_Float16)0.f, (_Float16)0.f, (_Float16)0.f,
                    (_Float16)0.f, (_Float16)0.f, (_Float16)0.f, (_Float16)0.f};
        h_v[0][t] = z;
    }
    __syncthreads();

    // ---- afrag fill: [G][hh][kt]; lane's A row = G*128 + 32w + 16hh + n,
    //      k-slice = kt*32 + lg*8 (same lane k-mapping as B; verified R11+) ----
    half8_ af[4][2][4];
#pragma unroll
    for (int G = 0; G < 4; ++G)
#pragma unroll
        for (int hh = 0; hh < 2; ++hh)
#pragma unroll
            for (int kt = 0; kt < 4; ++kt)
                af[G][hh][kt] = *(const half8_*)&whh_s[
                    (size_t)(G * HIDDEN + 32 * w + 16 * hh + n) * HIDDEN + kt * 32 + lg * 8];
    f32x4 ihxv[4][2];
#pragma unroll
    for (int G = 0; G < 4; ++G)
#pragma unroll
        for (int hh = 0; hh < 2; ++hh)
            ihxv[G][hh] = *(const f32x4*)&ihx_s[G * HIDDEN + 32 * w + 16 * hh + lg * 4];

    // Pin loop-invariants in VGPRs (anti-remat; proven harmless R15/16)
    asm volatile("" : "+v"(af[0][0][0]), "+v"(af[0][0][1]), "+v"(af[0][0][2]), "+v"(af[0][0][3]),
                      "+v"(af[0][1][0]), "+v"(af[0][1][1]), "+v"(af[0][1][2]), "+v"(af[0][1][3]));
    asm volatile("" : "+v"(af[1][0][0]), "+v"(af[1][0][1]), "+v"(af[1][0][2]), "+v"(af[1][0][3]),
                      "+v"(af[1][1][0]), "+v"(af[1][1][1]), "+v"(af[1][1][2]), "+v"(af[1][1][3]));
    asm volatile("" : "+v"(af[2][0][0]), "+v"(af[2][0][1]), "+v"(af[2][0][2]), "+v"(af[2][0][3]),
                      "+v"(af[2][1][0]), "+v"(af[2][1][1]), "+v"(af[2][1][2]), "+v"(af[2][1][3]));
    asm volatile("" : "+v"(af[3][0][0]), "+v"(af[3][0][1]), "+v"(af[3][0][2]), "+v"(af[3][0][3]),
                      "+v"(af[3][1][0]), "+v"(af[3][1][1]), "+v"(af[3][1][2]), "+v"(af[3][1][3]));
    asm volatile("" : "+v"(ihxv[0][0]), "+v"(ihxv[0][1]), "+v"(ihxv[1][0]), "+v"(ihxv[1][1]),
                      "+v"(ihxv[2][0]), "+v"(ihxv[2][1]), "+v"(ihxv[3][0]), "+v"(ihxv[3][1]));

    // activation lane-split: col n<8 handles cell 32w + 16*(n>>2) + lg*4 + (n&3)
    bool bh = (n & 4) != 0;   // hh select
    bool s1 = (n & 1) != 0, s2 = (n & 2) != 0;
    float c_own = 0.f;

    for (int d = 0; d < D_STEPS; ++d) {
        int rb = d & 1, wb = rb ^ 1;
        half8_ bf0 = h_v[rb][0 * 4 + lg];
        half8_ bf1 = h_v[rb][1 * 4 + lg];
        half8_ bf2 = h_v[rb][2 * 4 + lg];
        half8_ bf3 = h_v[rb][3 * 4 + lg];
        f32x4 a00 = ihxv[0][0], a01 = ihxv[0][1];
        f32x4 a10 = ihxv[1][0], a11 = ihxv[1][1];
        f32x4 a20 = ihxv[2][0], a21 = ihxv[2][1];
        f32x4 a30 = ihxv[3][0], a31 = ihxv[3][1];
#define MFMA __builtin_amdgcn_mfma_f32_16x16x32_f16
#define KSTEP(kt, bf) \
        a00 = MFMA(af[0][0][kt], bf, a00, 0, 0, 0); \
        a01 = MFMA(af[0][1][kt], bf, a01, 0, 0, 0); \
        a10 = MFMA(af[1][0][kt], bf, a10, 0, 0, 0); \
        a11 = MFMA(af[1][1][kt], bf, a11, 0, 0, 0); \
        a20 = MFMA(af[2][0][kt], bf, a20, 0, 0, 0); \
        a21 = MFMA(af[2][1][kt], bf, a21, 0, 0, 0); \
        a30 = MFMA(af[3][0][kt], bf, a30, 0, 0, 0); \
        a31 = MFMA(af[3][1][kt], bf, a31, 0, 0, 0);
        KSTEP(0, bf0)
        KSTEP(1, bf1)
        KSTEP(2, bf2)
        KSTEP(3, bf3)
#undef KSTEP
#undef MFMA
        // per-lane cell select: hh = bh, reg = (s2,s1)
#define PICK(v0, v1) (bh ? (s2 ? (s1 ? (v1)[3] : (v1)[2]) : (s1 ? (v1)[1] : (v1)[0])) \
                         : (s2 ? (s1 ? (v0)[3] : (v0)[2]) : (s1 ? (v0)[1] : (v0)[0])))
        float gi = PICK(a00, a01);
        float gf = PICK(a10, a11);
        float gg = PICK(a20, a21);
        float go = PICK(a30, a31);
#undef PICK
        float ig = rcp_(1.f + exp2_(-L2E * gi));
        float fg = rcp_(1.f + exp2_(-L2E * gf));
        float gt = 2.f * rcp_(1.f + exp2_(-2.f * L2E * gg)) - 1.f;
        float og = rcp_(1.f + exp2_(-L2E * go));
        c_own = fg * c_own + ig * gt;
        float th = 2.f * rcp_(1.f + exp2_(-2.f * L2E * c_own)) - 1.f;
        float h = og * th;
        if (n < 8) {
            int cell = 32 * w + 16 * (n >> 2) + lg * 4 + (n & 3);
            ((_Float16*)&h_v[wb][0])[cell] = (_Float16)h;
            if (d == b) h_keep[cell] = h;
        }
        __syncthreads();
    }

    // ---- logits for step d = b from h_keep (2 rows per thread) ----
#pragma unroll
    for (int rr = 0; rr < 2; ++rr) {
        int row = t + rr * 256;
        const float4* wl = (const float4*)(w_lin + (size_t)row * HIDDEN);
        float acc = b_lin[row];
#pragma unroll
        for (int k = 0; k < HIDDEN / 4; ++k) {
            float4 w4 = wl[k];
            acc += w4.x * h_keep[4 * k + 0] + w4.y * h_keep[4 * k + 1] +
                   w4.z * h_keep[4 * k + 2] + w4.w * h_keep[4 * k + 3];
        }
        out[b * N_ACT + row] = acc;
    }
}

extern "C" void kernel_launch(void* const* d_in, const int* in_sizes, int n_in,
                              void* d_out, int out_size, void* d_ws, size_t ws_size,
                              hipStream_t stream) {
    const float* x     = (const float*)d_in[0];
    const float* w_ih  = (const float*)d_in[1];
    const float* w_hh  = (const float*)d_in[2];
    const float* b_ih  = (const float*)d_in[3];
    const float* b_hh  = (const float*)d_in[4];
    const float* w_lin = (const float*)d_in[5];
    const float* b_lin = (const float*)d_in[6];
    float* out = (float*)d_out;

    float* partials = (float*)d_ws;      // 4096 floats

    k_ihx<<<2048, 256, 0, stream>>>(w_ih, x, partials);
    k_rec_logits<<<D_STEPS, 256, 0, stream>>>(w_hh, b_ih, b_hh, w_lin, b_lin,
                                              partials, out);
}

// Round 18
// 76.842 us; speedup vs baseline: 1.1022x; 1.1022x over previous
//
#include <hip/hip_runtime.h>
#include <hip/hip_bf16.h>

#define IN_SIZE 65536
#define HIDDEN 128
#define D_STEPS 64
#define N_ACT 512

typedef _Float16 half2_ __attribute__((ext_vector_type(2)));
typedef _Float16 half8_ __attribute__((ext_vector_type(8)));
typedef float f32x4 __attribute__((ext_vector_type(4)));

__device__ __forceinline__ float rcp_(float x) {
#if __has_builtin(__builtin_amdgcn_rcpf)
    return __builtin_amdgcn_rcpf(x);
#else
    return 1.f / x;
#endif
}
__device__ __forceinline__ float exp2_(float x) {
#if __has_builtin(__builtin_amdgcn_exp2f)
    return __builtin_amdgcn_exp2f(x);
#else
    return __exp2f(x);
#endif
}
#define L2E 1.44269504088896340736f

// ---------------- Kernel A: ihx partials (UNCHANGED from R9) ----------------
__global__ __launch_bounds__(256) void k_ihx(const float* __restrict__ w_ih,
                                             const float* __restrict__ x,
                                             float* __restrict__ partials) {
    int bid = blockIdx.x;
    int rp = bid >> 3;       // row pair 0..255
    int ck = bid & 7;        // chunk 0..7 (8192 cols each)
    int t = threadIdx.x;
    int r0 = 2 * rp, r1 = 2 * rp + 1;
    const float4* xp = (const float4*)(x + ck * 8192);
    const float4* w0 = (const float4*)(w_ih + (size_t)r0 * IN_SIZE + ck * 8192);
    const float4* w1 = (const float4*)(w_ih + (size_t)r1 * IN_SIZE + ck * 8192);

    float4 xv[8];
#pragma unroll
    for (int i = 0; i < 8; ++i) xv[i] = xp[t + i * 256];

    float a0 = 0.f, a1 = 0.f;
#pragma unroll
    for (int i = 0; i < 8; ++i) {
        float4 w4 = w0[t + i * 256];
        a0 += w4.x * xv[i].x + w4.y * xv[i].y + w4.z * xv[i].z + w4.w * xv[i].w;
    }
#pragma unroll
    for (int i = 0; i < 8; ++i) {
        float4 w4 = w1[t + i * 256];
        a1 += w4.x * xv[i].x + w4.y * xv[i].y + w4.z * xv[i].z + w4.w * xv[i].w;
    }
#pragma unroll
    for (int off = 32; off; off >>= 1) {
        a0 += __shfl_down(a0, off, 64);
        a1 += __shfl_down(a1, off, 64);
    }
    __shared__ float s[8];
    if ((t & 63) == 0) { s[t >> 6] = a0; s[4 + (t >> 6)] = a1; }
    __syncthreads();
    if (t == 0) {
        partials[r0 * 8 + ck] = s[0] + s[1] + s[2] + s[3];
        partials[r1 * 8 + ck] = s[4] + s[5] + s[6] + s[7];
    }
}

// ---------- Kernel B: R16 8-wave MFMA rec + logits, templated on NSTEPS ----
// R18 PROBE: extra NSTEPS=1 instance writes to ws scratch.
// dur - 69.7 = prologue cost (staging + afrag fill + ihx read).
// R17 lesson: keep 2 waves/SIMD (8 waves) — 1 wave/SIMD exposes all latency.
template <int NSTEPS>
__global__ __attribute__((amdgpu_flat_work_group_size(512, 512)))
__attribute__((amdgpu_waves_per_eu(2, 2)))
void k_rec_logits(
    const float* __restrict__ w_hh,
    const float* __restrict__ b_ih,
    const float* __restrict__ b_hh,
    const float* __restrict__ w_lin,
    const float* __restrict__ b_lin,
    const float* __restrict__ partials,
    float* __restrict__ outp) {
    int t = threadIdx.x;
    int b = blockIdx.x;      // 0..63
    int w = t >> 6;          // wave 0..7
    int l = t & 63;
    int lg = l >> 4;         // lane group 0..3
    int lm = l & 15;

    __shared__ _Float16 whh_s[4 * HIDDEN * HIDDEN];  // 128 KB, f16 w_hh
    __shared__ half8_ h_v[2][16];                    // h, double-buffered
    __shared__ float h_keep[HIDDEN];
    __shared__ float ihx_s[4 * HIDDEN];              // 2 KB

    // ---- stage w_hh -> LDS as f16 (coalesced float2 stream) ----
    {
        const float2* src = (const float2*)w_hh;     // 32768 float2
        half2_* dst = (half2_*)whh_s;
#pragma unroll 4
        for (int i = 0; i < 64; ++i) {
            float2 v = src[i * 512 + t];
            half2_ p = {(_Float16)v.x, (_Float16)v.y};
            dst[i * 512 + t] = p;
        }
    }
    // ---- ihx -> LDS (thread t owns row t) ----
    {
        const float4* pp = (const float4*)(partials + t * 8);
        float4 p0 = pp[0], p1 = pp[1];
        ihx_s[t] = p0.x + p0.y + p0.z + p0.w + p1.x + p1.y + p1.z + p1.w +
                   b_ih[t] + b_hh[t];
    }
    if (t < 16) {
        half8_ z = {(_Float16)0.f, (_Float16)0.f, (_Float16)0.f, (_Float16)0.f,
                    (_Float16)0.f, (_Float16)0.f, (_Float16)0.f, (_Float16)0.f};
        h_v[0][t] = z;
    }
    __syncthreads();

    // ---- fill afrag + ihx vectors ONCE, pin in VGPRs ----
    half8_ afrag[4][4];
#pragma unroll
    for (int G = 0; G < 4; ++G) {
#pragma unroll
        for (int kt = 0; kt < 4; ++kt) {
            afrag[G][kt] = *(const half8_*)&whh_s[(size_t)(G * HIDDEN + 16 * w + lm) * HIDDEN
                                                  + kt * 32 + lg * 8];
        }
    }
    f32x4 ihxv[4];
#pragma unroll
    for (int G = 0; G < 4; ++G)
        ihxv[G] = *(const f32x4*)&ihx_s[G * HIDDEN + 16 * w + lg * 4];

    asm volatile(""
        : "+v"(afrag[0][0]), "+v"(afrag[0][1]), "+v"(afrag[0][2]), "+v"(afrag[0][3]),
          "+v"(afrag[1][0]), "+v"(afrag[1][1]), "+v"(afrag[1][2]), "+v"(afrag[1][3]),
          "+v"(afrag[2][0]), "+v"(afrag[2][1]), "+v"(afrag[2][2]), "+v"(afrag[2][3]),
          "+v"(afrag[3][0]), "+v"(afrag[3][1]), "+v"(afrag[3][2]), "+v"(afrag[3][3]),
          "+v"(ihxv[0]), "+v"(ihxv[1]), "+v"(ihxv[2]), "+v"(ihxv[3]));

    int r2 = lm & 3;
    bool s1 = (r2 & 1) != 0, s2 = (r2 & 2) != 0;
    float c_own = 0.f;

    for (int d = 0; d < NSTEPS; ++d) {
        int rb = d & 1, wb = rb ^ 1;
        half8_ bf0 = h_v[rb][0 * 4 + lg];
        half8_ bf1 = h_v[rb][1 * 4 + lg];
        half8_ bf2 = h_v[rb][2 * 4 + lg];
        half8_ bf3 = h_v[rb][3 * 4 + lg];
        f32x4 ai_ = ihxv[0];
        f32x4 af_ = ihxv[1];
        f32x4 ag_ = ihxv[2];
        f32x4 ao_ = ihxv[3];
#define MFMA __builtin_amdgcn_mfma_f32_16x16x32_f16
        ai_ = MFMA(afrag[0][0], bf0, ai_, 0, 0, 0);
        af_ = MFMA(afrag[1][0], bf0, af_, 0, 0, 0);
        ag_ = MFMA(afrag[2][0], bf0, ag_, 0, 0, 0);
        ao_ = MFMA(afrag[3][0], bf0, ao_, 0, 0, 0);
        ai_ = MFMA(afrag[0][1], bf1, ai_, 0, 0, 0);
        af_ = MFMA(afrag[1][1], bf1, af_, 0, 0, 0);
        ag_ = MFMA(afrag[2][1], bf1, ag_, 0, 0, 0);
        ao_ = MFMA(afrag[3][1], bf1, ao_, 0, 0, 0);
        ai_ = MFMA(afrag[0][2], bf2, ai_, 0, 0, 0);
        af_ = MFMA(afrag[1][2], bf2, af_, 0, 0, 0);
        ag_ = MFMA(afrag[2][2], bf2, ag_, 0, 0, 0);
        ao_ = MFMA(afrag[3][2], bf2, ao_, 0, 0, 0);
        ai_ = MFMA(afrag[0][3], bf3, ai_, 0, 0, 0);
        af_ = MFMA(afrag[1][3], bf3, af_, 0, 0, 0);
        ag_ = MFMA(afrag[2][3], bf3, ag_, 0, 0, 0);
        ao_ = MFMA(afrag[3][3], bf3, ao_, 0, 0, 0);
#undef MFMA
        float gi = s2 ? (s1 ? ai_[3] : ai_[2]) : (s1 ? ai_[1] : ai_[0]);
        float gf = s2 ? (s1 ? af_[3] : af_[2]) : (s1 ? af_[1] : af_[0]);
        float gg = s2 ? (s1 ? ag_[3] : ag_[2]) : (s1 ? ag_[1] : ag_[0]);
        float go = s2 ? (s1 ? ao_[3] : ao_[2]) : (s1 ? ao_[1] : ao_[0]);
        float ig = rcp_(1.f + exp2_(-L2E * gi));
        float fg = rcp_(1.f + exp2_(-L2E * gf));
        float gt = 2.f * rcp_(1.f + exp2_(-2.f * L2E * gg)) - 1.f;
        float og = rcp_(1.f + exp2_(-L2E * go));
        c_own = fg * c_own + ig * gt;
        float th = 2.f * rcp_(1.f + exp2_(-2.f * L2E * c_own)) - 1.f;
        float h = og * th;
        if (lm < 4) {
            int cell = 16 * w + lg * 4 + r2;
            ((_Float16*)&h_v[wb][0])[cell] = (_Float16)h;
            if (d == b) h_keep[cell] = h;
        }
        __syncthreads();
    }

    if (NSTEPS == D_STEPS) {
        // ---- logits for step d = b from h_keep ----
        const float4* wl = (const float4*)(w_lin + (size_t)t * HIDDEN);
        float acc = b_lin[t];
#pragma unroll
        for (int k = 0; k < HIDDEN / 4; ++k) {
            float4 w4 = wl[k];
            acc += w4.x * h_keep[4 * k + 0] + w4.y * h_keep[4 * k + 1] +
                   w4.z * h_keep[4 * k + 2] + w4.w * h_keep[4 * k + 3];
        }
        outp[b * N_ACT + t] = acc;
    } else {
        // probe variant: keep state live, write h to scratch (not d_out)
        if (t < 16) outp[b * 16 + t] = (float)((_Float16*)&h_v[NSTEPS & 1][0])[t * 8];
    }
}

extern "C" void kernel_launch(void* const* d_in, const int* in_sizes, int n_in,
                              void* d_out, int out_size, void* d_ws, size_t ws_size,
                              hipStream_t stream) {
    const float* x     = (const float*)d_in[0];
    const float* w_ih  = (const float*)d_in[1];
    const float* w_hh  = (const float*)d_in[2];
    const float* b_ih  = (const float*)d_in[3];
    const float* b_hh  = (const float*)d_in[4];
    const float* w_lin = (const float*)d_in[5];
    const float* b_lin = (const float*)d_in[6];
    float* out = (float*)d_out;

    float* partials = (float*)d_ws;      // 4096 floats
    float* scratch  = (float*)d_ws + 8192;

    k_ihx<<<2048, 256, 0, stream>>>(w_ih, x, partials);
    // PROBE: 1-step instance -> scratch. dur - 69.7 = prologue cost.
    k_rec_logits<1><<<D_STEPS, 512, 0, stream>>>(w_hh, b_ih, b_hh, w_lin, b_lin,
                                                 partials, scratch);
    k_rec_logits<D_STEPS><<<D_STEPS, 512, 0, stream>>>(w_hh, b_ih, b_hh, w_lin, b_lin,
                                                       partials, out);
}

// Round 19
// 70.054 us; speedup vs baseline: 1.2090x; 1.0969x over previous
//
#include <hip/hip_runtime.h>
#include <hip/hip_bf16.h>

#define IN_SIZE 65536
#define HIDDEN 128
#define D_STEPS 64
#define N_ACT 512

typedef _Float16 half2_ __attribute__((ext_vector_type(2)));
typedef _Float16 half4_ __attribute__((ext_vector_type(4)));
typedef _Float16 half8_ __attribute__((ext_vector_type(8)));
typedef float f32x4 __attribute__((ext_vector_type(4)));

__device__ __forceinline__ float rcp_(float x) {
#if __has_builtin(__builtin_amdgcn_rcpf)
    return __builtin_amdgcn_rcpf(x);
#else
    return 1.f / x;
#endif
}
__device__ __forceinline__ float exp2_(float x) {
#if __has_builtin(__builtin_amdgcn_exp2f)
    return __builtin_amdgcn_exp2f(x);
#else
    return __exp2f(x);
#endif
}
#define L2E 1.44269504088896340736f

// -------- Kernel A: ihx partials + w_hh->f16 convert (32-float slice/block) ----
__global__ __launch_bounds__(256) void k_ihx(const float* __restrict__ w_ih,
                                             const float* __restrict__ x,
                                             const float* __restrict__ w_hh,
                                             float* __restrict__ partials,
                                             _Float16* __restrict__ whh16) {
    int bid = blockIdx.x;
    int t = threadIdx.x;
    // fold w_hh conversion in: 2048 blocks x 8 float4 = all 65536 elements
    if (t < 8) {
        float4 v = ((const float4*)w_hh)[bid * 8 + t];
        half4_ p = {(_Float16)v.x, (_Float16)v.y, (_Float16)v.z, (_Float16)v.w};
        ((half4_*)whh16)[bid * 8 + t] = p;
    }
    int rp = bid >> 3;       // row pair 0..255
    int ck = bid & 7;        // chunk 0..7 (8192 cols each)
    int r0 = 2 * rp, r1 = 2 * rp + 1;
    const float4* xp = (const float4*)(x + ck * 8192);
    const float4* w0 = (const float4*)(w_ih + (size_t)r0 * IN_SIZE + ck * 8192);
    const float4* w1 = (const float4*)(w_ih + (size_t)r1 * IN_SIZE + ck * 8192);

    float4 xv[8];
#pragma unroll
    for (int i = 0; i < 8; ++i) xv[i] = xp[t + i * 256];

    float a0 = 0.f, a1 = 0.f;
#pragma unroll
    for (int i = 0; i < 8; ++i) {
        float4 w4 = w0[t + i * 256];
        a0 += w4.x * xv[i].x + w4.y * xv[i].y + w4.z * xv[i].z + w4.w * xv[i].w;
    }
#pragma unroll
    for (int i = 0; i < 8; ++i) {
        float4 w4 = w1[t + i * 256];
        a1 += w4.x * xv[i].x + w4.y * xv[i].y + w4.z * xv[i].z + w4.w * xv[i].w;
    }
#pragma unroll
    for (int off = 32; off; off >>= 1) {
        a0 += __shfl_down(a0, off, 64);
        a1 += __shfl_down(a1, off, 64);
    }
    __shared__ float s[8];
    if ((t & 63) == 0) { s[t >> 6] = a0; s[4 + (t >> 6)] = a1; }
    __syncthreads();
    if (t == 0) {
        partials[r0 * 8 + ck] = s[0] + s[1] + s[2] + s[3];
        partials[r1 * 8 + ck] = s[4] + s[5] + s[6] + s[7];
    }
}

// ---------- Kernel B: MFMA rec + logits. R16 structure, three changes: ----
// (1) afrag fills via 16 direct global dwordx4 from pre-converted whh16 (no
//     128 KB LDS staging, no convert transients -> prologue 5.5 -> ~2 us);
// (2) K-split accumulators: two 2-deep MFMA chains + f32x4 add per gate
//     (accs live in AGPRs; saves ~2 MFMA-latencies per step);
// (3) unconditional h_all[64][128] LDS history (no d==b branch; logits read
//     h_all[b]). R17 lesson: keep 8 waves = 2 waves/SIMD.
__global__ __attribute__((amdgpu_flat_work_group_size(512, 512)))
__attribute__((amdgpu_waves_per_eu(2, 2)))
void k_rec_logits(
    const _Float16* __restrict__ whh16,
    const float* __restrict__ b_ih,
    const float* __restrict__ b_hh,
    const float* __restrict__ w_lin,
    const float* __restrict__ b_lin,
    const float* __restrict__ partials,
    float* __restrict__ out) {
    int t = threadIdx.x;
    int b = blockIdx.x;      // 0..63
    int w = t >> 6;          // wave 0..7
    int l = t & 63;
    int lg = l >> 4;         // lane group 0..3
    int lm = l & 15;

    __shared__ half8_ h_v[2][16];                 // h f16, double-buffered
    __shared__ float h_all[D_STEPS][HIDDEN];      // 32 KB history
    __shared__ float ihx_s[4 * HIDDEN];           // 2 KB

    // ---- afrag: 16 direct global 16B loads into the fragment registers ----
    half8_ afrag[4][4];
#pragma unroll
    for (int G = 0; G < 4; ++G)
#pragma unroll
        for (int kt = 0; kt < 4; ++kt)
            afrag[G][kt] = *(const half8_*)&whh16[(size_t)(G * HIDDEN + 16 * w + lm) * HIDDEN
                                                  + kt * 32 + lg * 8];
    // ---- ihx -> LDS (thread t owns row t) ----
    {
        const float4* pp = (const float4*)(partials + t * 8);
        float4 p0 = pp[0], p1 = pp[1];
        ihx_s[t] = p0.x + p0.y + p0.z + p0.w + p1.x + p1.y + p1.z + p1.w +
                   b_ih[t] + b_hh[t];
    }
    if (t < 16) {
        half8_ z = {(_Float16)0.f, (_Float16)0.f, (_Float16)0.f, (_Float16)0.f,
                    (_Float16)0.f, (_Float16)0.f, (_Float16)0.f, (_Float16)0.f};
        h_v[0][t] = z;
    }
    __syncthreads();

    f32x4 ihxv[4];
#pragma unroll
    for (int G = 0; G < 4; ++G)
        ihxv[G] = *(const f32x4*)&ihx_s[G * HIDDEN + 16 * w + lg * 4];

    asm volatile(""
        : "+v"(afrag[0][0]), "+v"(afrag[0][1]), "+v"(afrag[0][2]), "+v"(afrag[0][3]),
          "+v"(afrag[1][0]), "+v"(afrag[1][1]), "+v"(afrag[1][2]), "+v"(afrag[1][3]),
          "+v"(afrag[2][0]), "+v"(afrag[2][1]), "+v"(afrag[2][2]), "+v"(afrag[2][3]),
          "+v"(afrag[3][0]), "+v"(afrag[3][1]), "+v"(afrag[3][2]), "+v"(afrag[3][3]),
          "+v"(ihxv[0]), "+v"(ihxv[1]), "+v"(ihxv[2]), "+v"(ihxv[3]));

    int r2 = lm & 3;
    bool s1 = (r2 & 1) != 0, s2 = (r2 & 2) != 0;
    float c_own = 0.f;
    const f32x4 zr = {0.f, 0.f, 0.f, 0.f};

    for (int d = 0; d < D_STEPS; ++d) {
        int rb = d & 1, wb = rb ^ 1;
        half8_ bf0 = h_v[rb][0 * 4 + lg];
        half8_ bf1 = h_v[rb][1 * 4 + lg];
        half8_ bf2 = h_v[rb][2 * 4 + lg];
        half8_ bf3 = h_v[rb][3 * 4 + lg];
#define MFMA __builtin_amdgcn_mfma_f32_16x16x32_f16
        // K-split: chain a = kt{0,2} (seeded with ihx), chain b = kt{1,3}
        f32x4 ai_a = MFMA(afrag[0][0], bf0, ihxv[0], 0, 0, 0);
        f32x4 af_a = MFMA(afrag[1][0], bf0, ihxv[1], 0, 0, 0);
        f32x4 ag_a = MFMA(afrag[2][0], bf0, ihxv[2], 0, 0, 0);
        f32x4 ao_a = MFMA(afrag[3][0], bf0, ihxv[3], 0, 0, 0);
        f32x4 ai_b = MFMA(afrag[0][1], bf1, zr, 0, 0, 0);
        f32x4 af_b = MFMA(afrag[1][1], bf1, zr, 0, 0, 0);
        f32x4 ag_b = MFMA(afrag[2][1], bf1, zr, 0, 0, 0);
        f32x4 ao_b = MFMA(afrag[3][1], bf1, zr, 0, 0, 0);
        ai_a = MFMA(afrag[0][2], bf2, ai_a, 0, 0, 0);
        af_a = MFMA(afrag[1][2], bf2, af_a, 0, 0, 0);
        ag_a = MFMA(afrag[2][2], bf2, ag_a, 0, 0, 0);
        ao_a = MFMA(afrag[3][2], bf2, ao_a, 0, 0, 0);
        ai_b = MFMA(afrag[0][3], bf3, ai_b, 0, 0, 0);
        af_b = MFMA(afrag[1][3], bf3, af_b, 0, 0, 0);
        ag_b = MFMA(afrag[2][3], bf3, ag_b, 0, 0, 0);
        ao_b = MFMA(afrag[3][3], bf3, ao_b, 0, 0, 0);
#undef MFMA
        f32x4 ai_ = ai_a + ai_b;
        f32x4 af_ = af_a + af_b;
        f32x4 ag_ = ag_a + ag_b;
        f32x4 ao_ = ao_a + ao_b;
        float gi = s2 ? (s1 ? ai_[3] : ai_[2]) : (s1 ? ai_[1] : ai_[0]);
        float gf = s2 ? (s1 ? af_[3] : af_[2]) : (s1 ? af_[1] : af_[0]);
        float gg = s2 ? (s1 ? ag_[3] : ag_[2]) : (s1 ? ag_[1] : ag_[0]);
        float go = s2 ? (s1 ? ao_[3] : ao_[2]) : (s1 ? ao_[1] : ao_[0]);
        float ig = rcp_(1.f + exp2_(-L2E * gi));
        float fg = rcp_(1.f + exp2_(-L2E * gf));
        float gt = 2.f * rcp_(1.f + exp2_(-2.f * L2E * gg)) - 1.f;
        float og = rcp_(1.f + exp2_(-L2E * go));
        c_own = fg * c_own + ig * gt;
        float th = 2.f * rcp_(1.f + exp2_(-2.f * L2E * c_own)) - 1.f;
        float h = og * th;
        if (lm < 4) {
            int cell = 16 * w + lg * 4 + r2;
            ((_Float16*)&h_v[wb][0])[cell] = (_Float16)h;
            h_all[d][cell] = h;
        }
        __syncthreads();
    }

    // ---- logits for step d = b from h_all[b] ----
    {
        const float* hs = h_all[b];
        const float4* wl = (const float4*)(w_lin + (size_t)t * HIDDEN);
        float acc = b_lin[t];
#pragma unroll
        for (int k = 0; k < HIDDEN / 4; ++k) {
            float4 w4 = wl[k];
            acc += w4.x * hs[4 * k + 0] + w4.y * hs[4 * k + 1] +
                   w4.z * hs[4 * k + 2] + w4.w * hs[4 * k + 3];
        }
        out[b * N_ACT + t] = acc;
    }
}

extern "C" void kernel_launch(void* const* d_in, const int* in_sizes, int n_in,
                              void* d_out, int out_size, void* d_ws, size_t ws_size,
                              hipStream_t stream) {
    const float* x     = (const float*)d_in[0];
    const float* w_ih  = (const float*)d_in[1];
    const float* w_hh  = (const float*)d_in[2];
    const float* b_ih  = (const float*)d_in[3];
    const float* b_hh  = (const float*)d_in[4];
    const float* w_lin = (const float*)d_in[5];
    const float* b_lin = (const float*)d_in[6];
    float* out = (float*)d_out;

    float* partials  = (float*)d_ws;                    // 4096 floats
    _Float16* whh16  = (_Float16*)((float*)d_ws + 4096); // 65536 f16 = 128 KB

    k_ihx<<<2048, 256, 0, stream>>>(w_ih, x, w_hh, partials, whh16);
    k_rec_logits<<<D_STEPS, 512, 0, stream>>>(whh16, b_ih, b_hh, w_lin, b_lin,
                                              partials, out);
}